// Round 5
// baseline (447.199 us; speedup 1.0000x reference)
//
#include <hip/hip_runtime.h>
#include <math.h>

// Sizes (fixed): B=16, L=1024, D=50, V=129, d=64, N=2, H=8, DK=8, DFF=128, CVE=8
// LN eps = 1e-14, MASK_ATTN = -1e-30 (~zero!), MASK_POOL = -1e30.

typedef __bf16 bf16x8 __attribute__((ext_vector_type(8)));
typedef __bf16 bf16x2 __attribute__((ext_vector_type(2)));
typedef float f32x16 __attribute__((ext_vector_type(16)));
typedef unsigned int uint4e __attribute__((ext_vector_type(4)));
typedef unsigned long long u64;

static __device__ __forceinline__ float wave_sum64(float x) {
#pragma unroll
    for (int off = 32; off > 0; off >>= 1) x += __shfl_xor(x, off, 64);
    return x;
}

// scalar casts (not manual bit-ops) so the compiler can fuse to v_cvt_pk_bf16_f32
static __device__ __forceinline__ unsigned pack2(float a, float b) {
    bf16x2 t; t[0] = (__bf16)a; t[1] = (__bf16)b;
    return __builtin_bit_cast(unsigned, t);
}

static __device__ __forceinline__ float exp2fast(float x) {
#if defined(__has_builtin) && __has_builtin(__builtin_amdgcn_exp2f)
    return __builtin_amdgcn_exp2f(x);
#else
    return exp2f(x);
#endif
}

// lo <- value held by the hi=0 lane of the (lane, lane^32) pair; hi_ <- hi=1 lane's value.
static __device__ __forceinline__ void plswap(unsigned v, unsigned& lo, unsigned& hi_) {
#if defined(__has_builtin) && __has_builtin(__builtin_amdgcn_permlane32_swap)
    auto r = __builtin_amdgcn_permlane32_swap(v, v, false, false);
    lo = r[0]; hi_ = r[1];
#else
    unsigned x = __shfl_xor(v, 32, 64);
    bool h = (threadIdx.x & 32) != 0;
    lo = h ? x : v;
    hi_ = h ? v : x;
#endif
}

// ---------------------------------------------------------------- embeddings
// 1 tanh per lane (lanes 0..15), broadcast via shuffles — was 16 tanh per lane.
__global__ __launch_bounds__(256) void embed_kernel(
    const float* __restrict__ times, const float* __restrict__ values,
    const int* __restrict__ varis, const float* __restrict__ emb,
    const float* __restrict__ vW1, const float* __restrict__ vb1, const float* __restrict__ vW2,
    const float* __restrict__ tW1, const float* __restrict__ tb1, const float* __restrict__ tW2,
    float* __restrict__ X, float* __restrict__ mask)
{
    int row = blockIdx.x * 4 + (threadIdx.x >> 6);  // (b*L + l)
    int c   = threadIdx.x & 63;
    float v = values[row];
    float t = times[row];
    int var = varis[row];
    if (c == 0) mask[row] = (var > 0) ? 1.0f : 0.0f;
    float th = 0.f;
    if (c < 8)       th = tanhf(fmaf(v, vW1[c], vb1[c]));
    else if (c < 16) th = tanhf(fmaf(t, tW1[c - 8], tb1[c - 8]));
    float acc = emb[var * 64 + c];
#pragma unroll
    for (int j = 0; j < 8; ++j) {
        acc = fmaf(__shfl(th, j, 64),     vW2[j * 64 + c], acc);
        acc = fmaf(__shfl(th, j + 8, 64), tW2[j * 64 + c], acc);
    }
    X[row * 64 + c] = acc;
}

// ---------------------------------------------------------------- demo encoder
__global__ __launch_bounds__(128) void demo_kernel(
    const float* __restrict__ demo, const float* __restrict__ dW1, const float* __restrict__ db1,
    const float* __restrict__ dW2, const float* __restrict__ db2, float* __restrict__ denc)
{
    __shared__ float sh[128];
    int b = blockIdx.x;
    int t = threadIdx.x;
    float a = db1[t];
    for (int j = 0; j < 50; ++j) a = fmaf(demo[b * 50 + j], dW1[j * 128 + t], a);
    sh[t] = tanhf(a);
    __syncthreads();
    if (t < 64) {
        float a2 = db2[t];
#pragma unroll 8
        for (int j = 0; j < 128; ++j) a2 = fmaf(sh[j], dW2[j * 64 + t], a2);
        denc[b * 64 + t] = tanhf(a2);
    }
}

// ---------------------------------------------------------------- qkv projection
// Produces attention-ready operands: q f32 [bh][l][8]; K masked bf16 [bh][l][8];
// V transposed bf16 [bh][dk][l]. Mask/convert work done ONCE here instead of 8x in attn.
__global__ __launch_bounds__(256) void qkv_kernel(
    const float* __restrict__ X, const float* __restrict__ mask,
    const float* __restrict__ Wq, const float* __restrict__ Wk, const float* __restrict__ Wv,
    float* __restrict__ q, __bf16* __restrict__ kbf, __bf16* __restrict__ vtb)
{
    __shared__ float sWq[4096], sWk[4096], sWv[4096], sX[1024];
    int tid = threadIdx.x;
    for (int idx = tid; idx < 4096; idx += 256) {
        int h = idx >> 9, c = (idx >> 3) & 63, kk = idx & 7;
        int l = c * 64 + h * 8 + kk;
        sWq[l] = Wq[idx];
        sWk[l] = Wk[idx];
        sWv[l] = Wv[idx];
    }
    int row0 = blockIdx.x * 16;
    for (int idx = tid; idx < 1024; idx += 256) sX[idx] = X[row0 * 64 + idx];
    __syncthreads();
    int lane = tid & 63;
#pragma unroll
    for (int iter = 0; iter < 4; ++iter) {
        int r = iter * 4 + (tid >> 6);
        float aq = 0.f, ak = 0.f, av = 0.f;
#pragma unroll 8
        for (int c = 0; c < 64; ++c) {
            float x = sX[r * 64 + c];
            aq = fmaf(x, sWq[c * 64 + lane], aq);
            ak = fmaf(x, sWk[c * 64 + lane], ak);
            av = fmaf(x, sWv[c * 64 + lane], av);
        }
        int grow = row0 + r;
        int b = grow >> 10, l = grow & 1023;
        int h = lane >> 3, kk = lane & 7;
        int bh = b * 8 + h;
        q[(bh * 1024 + l) * 8 + kk] = aq;
        float km = mask[grow];  // wave-uniform broadcast
        kbf[(bh * 1024 + l) * 8 + kk] = (__bf16)(km != 0.f ? ak : 0.f);
        vtb[bh * 8192 + kk * 1024 + l] = (__bf16)av;
    }
}

// ---------------------------------------------------------------- MFMA attention
// Swapped QK^T (A=K, B=Q), 32x32x16 bf16: softmax lane-local. No max-subtraction.
// Mask pre-folded into kbf. Q pre-scaled by log2e -> p = v_exp(s). psum free via
// ones-row (dk=8) in V^T A-operand. 2 q-groups per wave share every K/V ds_read and
// give 2 independent MFMA chains. 512 blocks: bh = blockIdx&127 so the 4 blocks of a
// bh land on the SAME XCD (128%8==0) -> K/V L2-resident.
__global__ __launch_bounds__(256) void attn_mfma_kernel(
    const float* __restrict__ q, const __bf16* __restrict__ kbf,
    const __bf16* __restrict__ vtb, float* __restrict__ O)
{
    __shared__ __align__(16) __bf16 sK[8192];       // [key][8]
    __shared__ __align__(16) __bf16 sVT[9 * 1032];  // rows 0..7 V^T (stride 1032), row 8 ones

    int tid = threadIdx.x;
    int bh = blockIdx.x & 127;
    int chunk = blockIdx.x >> 7;

    // stage K: 8192 bf16 = 2048 u64 (u64 = 4 bf16!), 8B lane stride -> conflict-free
    const u64* kg = (const u64*)(kbf + bh * 8192);
    u64* sKq = (u64*)sK;
#pragma unroll
    for (int i = 0; i < 8; ++i) sKq[i * 256 + tid] = kg[i * 256 + tid];
    // stage V^T: 8 rows x 1024 bf16 (= 256 u64/row) -> LDS rows of stride 1032 bf16 (258 u64)
    const u64* vg = (const u64*)(vtb + bh * 8192);
#pragma unroll
    for (int it = 0; it < 8; ++it) {
        int idx = it * 256 + tid;       // 0..2047 u64
        int r = idx >> 8, w = idx & 255;
        ((u64*)(sVT + r * 1032))[w] = vg[idx];
    }
    {   // ones row (dk=8): 1024 bf16 = 512 u32
        unsigned* p1 = (unsigned*)(sVT + 8 * 1032);
        p1[tid] = 0x3f803f80u;
        p1[256 + tid] = 0x3f803f80u;
    }
    __syncthreads();

    int lane = tid & 63;
    int wv   = tid >> 6;
    int hi   = lane >> 5;
    int l31  = lane & 31;
    float qs = hi ? 0.0f : 1.4426950408889634f;  // zero k=8..15 padding via scale

    int q0row = chunk * 256 + wv * 64 + l31;

    bf16x8 qf0, qf1;
    {
        const float* qp0 = q + (bh * 1024 + q0row) * 8;
        const float* qp1 = qp0 + 32 * 8;
        float4 a0 = *(const float4*)qp0, b0 = *(const float4*)(qp0 + 4);
        float4 a1 = *(const float4*)qp1, b1 = *(const float4*)(qp1 + 4);
        qf0[0] = (__bf16)(a0.x * qs); qf0[1] = (__bf16)(a0.y * qs);
        qf0[2] = (__bf16)(a0.z * qs); qf0[3] = (__bf16)(a0.w * qs);
        qf0[4] = (__bf16)(b0.x * qs); qf0[5] = (__bf16)(b0.y * qs);
        qf0[6] = (__bf16)(b0.z * qs); qf0[7] = (__bf16)(b0.w * qs);
        qf1[0] = (__bf16)(a1.x * qs); qf1[1] = (__bf16)(a1.y * qs);
        qf1[2] = (__bf16)(a1.z * qs); qf1[3] = (__bf16)(a1.w * qs);
        qf1[4] = (__bf16)(b1.x * qs); qf1[5] = (__bf16)(b1.y * qs);
        qf1[6] = (__bf16)(b1.z * qs); qf1[7] = (__bf16)(b1.w * qs);
    }

    f32x16 acc0, acc1, zc;
#pragma unroll
    for (int i = 0; i < 16; ++i) { acc0[i] = 0.f; acc1[i] = 0.f; zc[i] = 0.f; }

    const bf16x8* sKv = (const bf16x8*)sK;
    const __bf16* vbase = sVT + (l31 < 8 ? l31 : 8) * 1032;

#pragma unroll 2
    for (int kt = 0; kt < 32; ++kt) {
        bf16x8 kf = sKv[kt * 32 + l31];
        // S^T: reg r -> key = 32kt + (r&3)+8*(r>>2)+4*hi, query = l31 (per group)
        f32x16 st0 = __builtin_amdgcn_mfma_f32_32x32x16_bf16(kf, qf0, zc, 0, 0, 0);
        f32x16 st1 = __builtin_amdgcn_mfma_f32_32x32x16_bf16(kf, qf1, zc, 0, 0, 0);

        float p0[16], p1[16];
#pragma unroll
        for (int r = 0; r < 16; ++r) p0[r] = exp2fast(st0[r]);
#pragma unroll
        for (int r = 0; r < 16; ++r) p1[r] = exp2fast(st1[r]);

        unsigned L0a[4], H0a[4], L1a[4], H1a[4];
        unsigned L0b[4], H0b[4], L1b[4], H1b[4];
#pragma unroll
        for (int g = 0; g < 4; ++g) {
            plswap(pack2(p0[4 * g + 0], p0[4 * g + 1]), L0a[g], H0a[g]);
            plswap(pack2(p0[4 * g + 2], p0[4 * g + 3]), L1a[g], H1a[g]);
            plswap(pack2(p1[4 * g + 0], p1[4 * g + 1]), L0b[g], H0b[g]);
            plswap(pack2(p1[4 * g + 2], p1[4 * g + 3]), L1b[g], H1b[g]);
        }

#pragma unroll
        for (int h = 0; h < 2; ++h) {
            bf16x8 vf = *(const bf16x8*)(vbase + kt * 32 + 16 * h + 8 * hi);
            uint4e pw0, pw1;
            pw0[0] = hi ? L0a[2 * h + 1] : L0a[2 * h];
            pw0[1] = hi ? L1a[2 * h + 1] : L1a[2 * h];
            pw0[2] = hi ? H0a[2 * h + 1] : H0a[2 * h];
            pw0[3] = hi ? H1a[2 * h + 1] : H1a[2 * h];
            pw1[0] = hi ? L0b[2 * h + 1] : L0b[2 * h];
            pw1[1] = hi ? L1b[2 * h + 1] : L1b[2 * h];
            pw1[2] = hi ? H0b[2 * h + 1] : H0b[2 * h];
            pw1[3] = hi ? H1b[2 * h + 1] : H1b[2 * h];
            acc0 = __builtin_amdgcn_mfma_f32_32x32x16_bf16(vf, __builtin_bit_cast(bf16x8, pw0), acc0, 0, 0, 0);
            acc1 = __builtin_amdgcn_mfma_f32_32x32x16_bf16(vf, __builtin_bit_cast(bf16x8, pw1), acc1, 0, 0, 0);
        }
    }

    // acc[4] = ones-row output = psum (all lanes)
    float inv0 = 1.0f / acc0[4];
    float inv1 = 1.0f / acc1[4];
    float4 o0, o1;
    o0.x = acc0[0] * inv0; o0.y = acc0[1] * inv0; o0.z = acc0[2] * inv0; o0.w = acc0[3] * inv0;
    o1.x = acc1[0] * inv1; o1.y = acc1[1] * inv1; o1.z = acc1[2] * inv1; o1.w = acc1[3] * inv1;
    *(float4*)(O + (bh * 1024 + q0row) * 8 + 4 * hi) = o0;
    *(float4*)(O + (bh * 1024 + q0row + 32) * 8 + 4 * hi) = o1;
}

// ---------------------------------------------------------------- out-proj + residual + LN (wave = row)
__global__ __launch_bounds__(256) void proj_ln_kernel(
    float* __restrict__ X, const float* __restrict__ O, const float* __restrict__ Wo,
    const float* __restrict__ gamma, const float* __restrict__ beta, int gi)
{
    __shared__ float sWo[4096];
    __shared__ float so[4][64];
    int tid = threadIdx.x;
    for (int idx = tid; idx < 4096; idx += 256) sWo[idx] = Wo[idx];
    int row0 = blockIdx.x * 4;
    {
        int r = tid >> 6, j = tid & 63;
        int grow = row0 + r;
        int b = grow >> 10, l = grow & 1023;
        so[r][j] = O[((b * 8 + (j >> 3)) * 1024 + l) * 8 + (j & 7)];
    }
    __syncthreads();
    int r = tid >> 6, c = tid & 63;
    float acc = 0.f;
#pragma unroll 8
    for (int j = 0; j < 64; ++j) acc = fmaf(so[r][j], sWo[j * 64 + c], acc);
    float x = X[(row0 + r) * 64 + c] + acc;
    float mean = wave_sum64(x) * (1.0f / 64.0f);
    float dx = x - mean;
    float var = wave_sum64(dx * dx) * (1.0f / 64.0f);
    X[(row0 + r) * 64 + c] = dx * rsqrtf(var + 1e-14f) * gamma[gi] + beta[gi];
}

// ---------------------------------------------------------------- FFN + residual + LN
__global__ __launch_bounds__(256) void ffn_ln_kernel(
    float* __restrict__ X, const float* __restrict__ W1, const float* __restrict__ b1,
    const float* __restrict__ W2, const float* __restrict__ b2,
    const float* __restrict__ gamma, const float* __restrict__ beta, int gi)
{
    __shared__ float sW1[8192];  // [c][j]
    __shared__ float sW2[8192];  // [j][c]
    __shared__ float sX[1024];
    __shared__ float sh[2048];
    int tid = threadIdx.x;
    for (int idx = tid; idx < 8192; idx += 256) { sW1[idx] = W1[idx]; sW2[idx] = W2[idx]; }
    int row0 = blockIdx.x * 16;
    for (int idx = tid; idx < 1024; idx += 256) sX[idx] = X[row0 * 64 + idx];
    __syncthreads();
    for (int idx = tid; idx < 2048; idx += 256) {
        int r = idx >> 7, j = idx & 127;
        float a = b1[j];
#pragma unroll 8
        for (int c = 0; c < 64; ++c) a = fmaf(sX[r * 64 + c], sW1[c * 128 + j], a);
        sh[idx] = fmaxf(a, 0.0f);
    }
    __syncthreads();
#pragma unroll
    for (int iter = 0; iter < 4; ++iter) {
        int idx = iter * 256 + tid;
        int r = idx >> 6, c = idx & 63;
        float a = b2[c];
#pragma unroll 8
        for (int j = 0; j < 128; ++j) a = fmaf(sh[r * 128 + j], sW2[j * 64 + c], a);
        float x = sX[idx] + a;
        float mean = wave_sum64(x) * (1.0f / 64.0f);
        float dx = x - mean;
        float var = wave_sum64(dx * dx) * (1.0f / 64.0f);
        X[row0 * 64 + idx] = dx * rsqrtf(var + 1e-14f) * gamma[gi] + beta[gi];
    }
}

// ---------------------------------------------------------------- pooling attention weights
__global__ __launch_bounds__(256) void aw_kernel(
    const float* __restrict__ X, const float* __restrict__ aW1, const float* __restrict__ ab1,
    const float* __restrict__ aW2, float* __restrict__ aw)
{
    __shared__ float sW[8192];   // aW1 [c][j]
    __shared__ float sX[1024];
    __shared__ float sh[2048];
    int tid = threadIdx.x;
    for (int idx = tid; idx < 8192; idx += 256) sW[idx] = aW1[idx];
    int row0 = blockIdx.x * 16;
    for (int idx = tid; idx < 1024; idx += 256) sX[idx] = X[row0 * 64 + idx];
    __syncthreads();
    for (int idx = tid; idx < 2048; idx += 256) {
        int r = idx >> 7, j = idx & 127;
        float a = ab1[j];
#pragma unroll 8
        for (int c = 0; c < 64; ++c) a = fmaf(sX[r * 64 + c], sW[c * 128 + j], a);
        sh[idx] = tanhf(a) * aW2[j];
    }
    __syncthreads();
    {
        int r = tid >> 4, jj = tid & 15;
        float s = 0.f;
#pragma unroll
        for (int t = 0; t < 8; ++t) s += sh[r * 128 + jj * 8 + t];
#pragma unroll
        for (int off = 8; off > 0; off >>= 1) s += __shfl_xor(s, off, 64);
        if (jj == 0) aw[row0 + r] = s;
    }
}

// ---------------------------------------------------------------- masked pool softmax + final head
__global__ __launch_bounds__(256) void pool_kernel(
    const float* __restrict__ X, const float* __restrict__ aw,
    const float* __restrict__ mask, const float* __restrict__ denc,
    const float* __restrict__ Wout, const float* __restrict__ bout, float* __restrict__ out)
{
    __shared__ float sp[1024];
    __shared__ float red[8];
    __shared__ float sf[4][64];
    int b = blockIdx.x, tid = threadIdx.x;
    float mymax = -INFINITY;
    for (int idx = tid; idx < 1024; idx += 256) {
        float s = (mask[b * 1024 + idx] != 0.0f) ? aw[b * 1024 + idx] : -1e30f;
        sp[idx] = s;
        mymax = fmaxf(mymax, s);
    }
#pragma unroll
    for (int off = 32; off > 0; off >>= 1) mymax = fmaxf(mymax, __shfl_xor(mymax, off, 64));
    if ((tid & 63) == 0) red[tid >> 6] = mymax;
    __syncthreads();
    float gmax = fmaxf(fmaxf(red[0], red[1]), fmaxf(red[2], red[3]));
    float mysum = 0.f;
    for (int idx = tid; idx < 1024; idx += 256) {
        float p = __expf(sp[idx] - gmax);
        sp[idx] = p;
        mysum += p;
    }
    mysum = wave_sum64(mysum);
    if ((tid & 63) == 0) red[4 + (tid >> 6)] = mysum;
    __syncthreads();
    float inv = 1.0f / (red[4] + red[5] + red[6] + red[7]);
    int c = tid & 63, part = tid >> 6;
    float f = 0.f;
    for (int l = part; l < 1024; l += 4) f = fmaf(sp[l], X[(b * 1024 + l) * 64 + c], f);
    sf[part][c] = f;
    __syncthreads();
    if (tid < 64) {
        float fc = (sf[0][tid] + sf[1][tid] + sf[2][tid] + sf[3][tid]) * inv;
        float contrib = fc * Wout[tid] + denc[b * 64 + tid] * Wout[64 + tid];
        contrib = wave_sum64(contrib);
        if (tid == 0) out[b] = 1.0f / (1.0f + __expf(-(contrib + bout[0])));
    }
}

// ---------------------------------------------------------------- launch
extern "C" void kernel_launch(void* const* d_in, const int* in_sizes, int n_in,
                              void* d_out, int out_size, void* d_ws, size_t ws_size,
                              hipStream_t stream)
{
    const float* demo  = (const float*)d_in[0];
    const float* times = (const float*)d_in[1];
    const float* values= (const float*)d_in[2];
    const int*   varis = (const int*)d_in[3];
    const float* emb   = (const float*)d_in[4];
    const float* vW1   = (const float*)d_in[5];
    const float* vb1   = (const float*)d_in[6];
    const float* vW2   = (const float*)d_in[7];
    const float* tW1   = (const float*)d_in[8];
    const float* tb1   = (const float*)d_in[9];
    const float* tW2   = (const float*)d_in[10];
    const float* Wq    = (const float*)d_in[11];
    const float* Wk    = (const float*)d_in[12];
    const float* Wv    = (const float*)d_in[13];
    const float* Wo    = (const float*)d_in[14];
    const float* W1    = (const float*)d_in[15];
    const float* b1    = (const float*)d_in[16];
    const float* W2    = (const float*)d_in[17];
    const float* b2    = (const float*)d_in[18];
    const float* gamma = (const float*)d_in[19];
    const float* beta  = (const float*)d_in[20];
    const float* aW1   = (const float*)d_in[21];
    const float* ab1   = (const float*)d_in[22];
    const float* aW2   = (const float*)d_in[23];
    const float* dW1   = (const float*)d_in[24];
    const float* db1   = (const float*)d_in[25];
    const float* dW2   = (const float*)d_in[26];
    const float* db2   = (const float*)d_in[27];
    const float* Wout  = (const float*)d_in[28];
    const float* bout  = (const float*)d_in[29];
    float* out = (float*)d_out;

    float* ws   = (float*)d_ws;
    float* X    = ws;                       // 1048576 f
    float* mask = X + 1048576;              // 16384 f
    float* qb   = mask + 16384;             // 1048576 f
    __bf16* kbf = (__bf16*)(qb + 1048576);  // 1048576 bf16 (524288 f)
    __bf16* vtb = kbf + 1048576;            // 1048576 bf16 (524288 f)
    float* Ob   = (float*)(vtb + 1048576);  // 1048576 f
    float* awb  = Ob + 1048576;             // 16384 f
    float* denc = awb + 16384;              // 1024 f

    embed_kernel<<<4096, 256, 0, stream>>>(times, values, varis, emb, vW1, vb1, vW2, tW1, tb1, tW2, X, mask);
    demo_kernel<<<16, 128, 0, stream>>>(demo, dW1, db1, dW2, db2, denc);
    for (int i = 0; i < 2; ++i) {
        qkv_kernel<<<1024, 256, 0, stream>>>(X, mask, Wq + i * 4096, Wk + i * 4096, Wv + i * 4096,
                                             qb, kbf, vtb);
        attn_mfma_kernel<<<512, 256, 0, stream>>>(qb, kbf, vtb, Ob);
        proj_ln_kernel<<<4096, 256, 0, stream>>>(X, Ob, Wo + i * 4096, gamma, beta, 2 * i);
        ffn_ln_kernel<<<1024, 256, 0, stream>>>(X, W1 + i * 8192, b1 + i * 128, W2 + i * 8192, b2 + i * 64,
                                                gamma, beta, 2 * i + 1);
    }
    aw_kernel<<<1024, 256, 0, stream>>>(X, aW1, ab1, aW2, awb);
    pool_kernel<<<16, 256, 0, stream>>>(X, awb, mask, denc, Wout, bout, out);
}

// Round 6
// 410.389 us; speedup vs baseline: 1.0897x; 1.0897x over previous
//
#include <hip/hip_runtime.h>
#include <math.h>

// Sizes (fixed): B=16, L=1024, D=50, V=129, d=64, N=2, H=8, DK=8, DFF=128, CVE=8
// LN eps = 1e-14, MASK_ATTN = -1e-30 (~zero!), MASK_POOL = -1e30.

typedef __bf16 bf16x8 __attribute__((ext_vector_type(8)));
typedef __bf16 bf16x2 __attribute__((ext_vector_type(2)));
typedef float f32x16 __attribute__((ext_vector_type(16)));
typedef unsigned int uint4e __attribute__((ext_vector_type(4)));
typedef unsigned long long u64;

static __device__ __forceinline__ float wave_sum64(float x) {
#pragma unroll
    for (int off = 32; off > 0; off >>= 1) x += __shfl_xor(x, off, 64);
    return x;
}

static __device__ __forceinline__ unsigned pack2(float a, float b) {
    bf16x2 t; t[0] = (__bf16)a; t[1] = (__bf16)b;
    return __builtin_bit_cast(unsigned, t);
}

static __device__ __forceinline__ float exp2fast(float x) {
#if defined(__has_builtin) && __has_builtin(__builtin_amdgcn_exp2f)
    return __builtin_amdgcn_exp2f(x);
#else
    return exp2f(x);
#endif
}

// lo <- value held by the hi=0 lane of the (lane, lane^32) pair; hi_ <- hi=1 lane's value.
static __device__ __forceinline__ void plswap(unsigned v, unsigned& lo, unsigned& hi_) {
#if defined(__has_builtin) && __has_builtin(__builtin_amdgcn_permlane32_swap)
    auto r = __builtin_amdgcn_permlane32_swap(v, v, false, false);
    lo = r[0]; hi_ = r[1];
#else
    unsigned x = __shfl_xor(v, 32, 64);
    bool h = (threadIdx.x & 32) != 0;
    lo = h ? x : v;
    hi_ = h ? v : x;
#endif
}

// ---------------------------------------------------------------- embeddings
__global__ __launch_bounds__(256) void embed_kernel(
    const float* __restrict__ times, const float* __restrict__ values,
    const int* __restrict__ varis, const float* __restrict__ emb,
    const float* __restrict__ vW1, const float* __restrict__ vb1, const float* __restrict__ vW2,
    const float* __restrict__ tW1, const float* __restrict__ tb1, const float* __restrict__ tW2,
    float* __restrict__ X, float* __restrict__ mask)
{
    int row = blockIdx.x * 4 + (threadIdx.x >> 6);  // (b*L + l)
    int c   = threadIdx.x & 63;
    float v = values[row];
    float t = times[row];
    int var = varis[row];
    if (c == 0) mask[row] = (var > 0) ? 1.0f : 0.0f;
    float th = 0.f;
    if (c < 8)       th = tanhf(fmaf(v, vW1[c], vb1[c]));
    else if (c < 16) th = tanhf(fmaf(t, tW1[c - 8], tb1[c - 8]));
    float acc = emb[var * 64 + c];
#pragma unroll
    for (int j = 0; j < 8; ++j) {
        acc = fmaf(__shfl(th, j, 64),     vW2[j * 64 + c], acc);
        acc = fmaf(__shfl(th, j + 8, 64), tW2[j * 64 + c], acc);
    }
    X[row * 64 + c] = acc;
}

// ---------------------------------------------------------------- demo encoder
__global__ __launch_bounds__(128) void demo_kernel(
    const float* __restrict__ demo, const float* __restrict__ dW1, const float* __restrict__ db1,
    const float* __restrict__ dW2, const float* __restrict__ db2, float* __restrict__ denc)
{
    __shared__ float sh[128];
    int b = blockIdx.x;
    int t = threadIdx.x;
    float a = db1[t];
    for (int j = 0; j < 50; ++j) a = fmaf(demo[b * 50 + j], dW1[j * 128 + t], a);
    sh[t] = tanhf(a);
    __syncthreads();
    if (t < 64) {
        float a2 = db2[t];
#pragma unroll 8
        for (int j = 0; j < 128; ++j) a2 = fmaf(sh[j], dW2[j * 64 + t], a2);
        denc[b * 64 + t] = tanhf(a2);
    }
}

// ---------------------------------------------------------------- qkv projection
// Outputs: q bf16 pre-scaled by log2e [bh][l][8]; K masked bf16 [bh][l][8];
// V transposed bf16 [bh][dk][l] (written via LDS transpose -> coalesced u32 stores).
__global__ __launch_bounds__(256) void qkv_kernel(
    const float* __restrict__ X, const float* __restrict__ mask,
    const float* __restrict__ Wq, const float* __restrict__ Wk, const float* __restrict__ Wv,
    __bf16* __restrict__ qbf, __bf16* __restrict__ kbf, __bf16* __restrict__ vtb)
{
    __shared__ float sWq[4096], sWk[4096], sWv[4096], sX[1024];
    int tid = threadIdx.x;
    for (int idx = tid; idx < 4096; idx += 256) {
        int h = idx >> 9, c = (idx >> 3) & 63, kk = idx & 7;
        int l = c * 64 + h * 8 + kk;
        sWq[l] = Wq[idx];
        sWk[l] = Wk[idx];
        sWv[l] = Wv[idx];
    }
    int row0 = blockIdx.x * 16;
    for (int idx = tid; idx < 1024; idx += 256) sX[idx] = X[row0 * 64 + idx];
    __syncthreads();
    int lane = tid & 63;
    float avr[4];
#pragma unroll
    for (int iter = 0; iter < 4; ++iter) {
        int r = iter * 4 + (tid >> 6);
        float aq = 0.f, ak = 0.f, av = 0.f;
#pragma unroll 8
        for (int c = 0; c < 64; ++c) {
            float x = sX[r * 64 + c];
            aq = fmaf(x, sWq[c * 64 + lane], aq);
            ak = fmaf(x, sWk[c * 64 + lane], ak);
            av = fmaf(x, sWv[c * 64 + lane], av);
        }
        int grow = row0 + r;
        int b = grow >> 10, l = grow & 1023;
        int h = lane >> 3, kk = lane & 7;
        int bh = b * 8 + h;
        qbf[(bh * 1024 + l) * 8 + kk] = (__bf16)(aq * 1.4426950408889634f);
        float km = mask[grow];  // wave-uniform broadcast
        kbf[(bh * 1024 + l) * 8 + kk] = (__bf16)(km != 0.f ? ak : 0.f);
        avr[iter] = av;
    }
    __syncthreads();            // sX no longer needed; reuse as transpose buffer
    __bf16* sVt = (__bf16*)sX;  // [64][18] (stride 18 -> 9-dword rows, 2-way-free banks)
#pragma unroll
    for (int iter = 0; iter < 4; ++iter) {
        int r = iter * 4 + (tid >> 6);
        sVt[lane * 18 + r] = (__bf16)avr[iter];
    }
    __syncthreads();
    int b = row0 >> 10, l0 = row0 & 1023;
#pragma unroll
    for (int it = 0; it < 2; ++it) {
        int idx = it * 256 + tid;   // 0..511 -> (hkk, lpair)
        int hkk = idx >> 3, lp = idx & 7;
        unsigned w = ((const unsigned*)sVt)[hkk * 9 + lp];
        int h = hkk >> 3, kk = hkk & 7;
        ((unsigned*)(vtb + (b * 8 + h) * 8192 + kk * 1024 + l0))[lp] = w;
    }
}

// ---------------------------------------------------------------- MFMA attention (split-K x4)
// Swapped QK^T (A=K, B=Q), 32x32x16 bf16: softmax lane-local. No max-subtraction, so
// split-K partials combine trivially: store unnormalized (P.V, sum P) per split; the
// combine happens in proj_ln. psum free via ones-row (dk=8) in the V^T A-operand.
// Grid 2048 = 4 splits x 4 chunks x 128 bh -> 8192 waves = 8/SIMD (max occupancy).
// bh = blockIdx&127 keeps all blocks of a bh on one XCD (L2-resident K/V).
__global__ __launch_bounds__(256) void attn_mfma_kernel(
    const __bf16* __restrict__ qbf, const __bf16* __restrict__ kbf,
    const __bf16* __restrict__ vtb, float* __restrict__ Opart, float* __restrict__ ssum)
{
    __shared__ __align__(16) __bf16 sK[256 * 8];    // 4KB: keys of this split
    __shared__ __align__(16) __bf16 sVT[9 * 264];   // rows 0..7 V^T (stride 264), row 8 ones

    int tid   = threadIdx.x;
    int bh    = blockIdx.x & 127;
    int chunk = (blockIdx.x >> 7) & 3;
    int s     = blockIdx.x >> 9;

    const u64* kg = (const u64*)(kbf + bh * 8192 + s * 2048);
    u64* sKq = (u64*)sK;
    sKq[tid]       = kg[tid];
    sKq[256 + tid] = kg[256 + tid];

    const u64* vgb = (const u64*)(vtb + bh * 8192 + s * 256);
#pragma unroll
    for (int it = 0; it < 2; ++it) {
        int idx = it * 256 + tid;   // 0..511: r = dk row, w = u64 within 256-key segment
        int r = idx >> 6, w = idx & 63;
        ((u64*)(sVT + r * 264))[w] = vgb[r * 256 + w];
    }
    if (tid < 128) ((unsigned*)(sVT + 8 * 264))[tid] = 0x3f803f80u;  // ones row
    __syncthreads();

    int lane = tid & 63;
    int wv   = tid >> 6;
    int hi   = lane >> 5;
    int l31  = lane & 31;
    unsigned hm = hi ? 0u : 0xffffffffu;   // hi lanes supply zero (k=8..15 padding)

    int q0row = chunk * 256 + wv * 64 + l31;

    bf16x8 qf0, qf1;
    {
        const __bf16* qp = qbf + (bh * 1024 + q0row) * 8;
        uint4e qa = *(const uint4e*)qp;
        uint4e qb2 = *(const uint4e*)(qp + 256);   // +32 queries
        qa[0] &= hm; qa[1] &= hm; qa[2] &= hm; qa[3] &= hm;
        qb2[0] &= hm; qb2[1] &= hm; qb2[2] &= hm; qb2[3] &= hm;
        qf0 = __builtin_bit_cast(bf16x8, qa);
        qf1 = __builtin_bit_cast(bf16x8, qb2);
    }

    f32x16 acc0, acc1, zc;
#pragma unroll
    for (int i = 0; i < 16; ++i) { acc0[i] = 0.f; acc1[i] = 0.f; zc[i] = 0.f; }

    const bf16x8* sKv = (const bf16x8*)sK;
    const __bf16* vbase = sVT + (l31 < 8 ? l31 : 8) * 264;

#pragma unroll 2
    for (int kt = 0; kt < 8; ++kt) {
        bf16x8 kf = sKv[kt * 32 + l31];
        f32x16 st0 = __builtin_amdgcn_mfma_f32_32x32x16_bf16(kf, qf0, zc, 0, 0, 0);
        f32x16 st1 = __builtin_amdgcn_mfma_f32_32x32x16_bf16(kf, qf1, zc, 0, 0, 0);

        float p0[16], p1[16];
#pragma unroll
        for (int r = 0; r < 16; ++r) p0[r] = exp2fast(st0[r]);
#pragma unroll
        for (int r = 0; r < 16; ++r) p1[r] = exp2fast(st1[r]);

        unsigned L0a[4], H0a[4], L1a[4], H1a[4];
        unsigned L0b[4], H0b[4], L1b[4], H1b[4];
#pragma unroll
        for (int g = 0; g < 4; ++g) {
            plswap(pack2(p0[4 * g + 0], p0[4 * g + 1]), L0a[g], H0a[g]);
            plswap(pack2(p0[4 * g + 2], p0[4 * g + 3]), L1a[g], H1a[g]);
            plswap(pack2(p1[4 * g + 0], p1[4 * g + 1]), L0b[g], H0b[g]);
            plswap(pack2(p1[4 * g + 2], p1[4 * g + 3]), L1b[g], H1b[g]);
        }

#pragma unroll
        for (int h = 0; h < 2; ++h) {
            bf16x8 vf = *(const bf16x8*)(vbase + kt * 32 + 16 * h + 8 * hi);
            uint4e pw0, pw1;
            pw0[0] = hi ? L0a[2 * h + 1] : L0a[2 * h];
            pw0[1] = hi ? L1a[2 * h + 1] : L1a[2 * h];
            pw0[2] = hi ? H0a[2 * h + 1] : H0a[2 * h];
            pw0[3] = hi ? H1a[2 * h + 1] : H1a[2 * h];
            pw1[0] = hi ? L0b[2 * h + 1] : L0b[2 * h];
            pw1[1] = hi ? L1b[2 * h + 1] : L1b[2 * h];
            pw1[2] = hi ? H0b[2 * h + 1] : H0b[2 * h];
            pw1[3] = hi ? H1b[2 * h + 1] : H1b[2 * h];
            acc0 = __builtin_amdgcn_mfma_f32_32x32x16_bf16(vf, __builtin_bit_cast(bf16x8, pw0), acc0, 0, 0, 0);
            acc1 = __builtin_amdgcn_mfma_f32_32x32x16_bf16(vf, __builtin_bit_cast(bf16x8, pw1), acc1, 0, 0, 0);
        }
    }

    // unnormalized partials; acc[4] = ones-row output = sum P (all lanes)
    int obase = ((s * 128 + bh) * 1024 + q0row) * 8 + 4 * hi;
    float4 o0, o1;
    o0.x = acc0[0]; o0.y = acc0[1]; o0.z = acc0[2]; o0.w = acc0[3];
    o1.x = acc1[0]; o1.y = acc1[1]; o1.z = acc1[2]; o1.w = acc1[3];
    *(float4*)(Opart + obase) = o0;
    *(float4*)(Opart + obase + 256) = o1;
    if (!hi) {
        int sb = (s * 128 + bh) * 1024 + q0row;
        ssum[sb] = acc0[4];
        ssum[sb + 32] = acc1[4];
    }
}

// ---------------------------------------------------------------- out-proj + residual + LN
// Folds the split-K combine: O = (sum_s Opart) / (sum_s ssum).
__global__ __launch_bounds__(256) void proj_ln_kernel(
    float* __restrict__ X, const float* __restrict__ Opart, const float* __restrict__ ssum,
    const float* __restrict__ Wo, const float* __restrict__ gamma, const float* __restrict__ beta,
    int gi)
{
    __shared__ float sWo[4096];
    __shared__ float so[4][64];
    int tid = threadIdx.x;
    for (int idx = tid; idx < 4096; idx += 256) sWo[idx] = Wo[idx];
    int row0 = blockIdx.x * 4;
    {
        int r = tid >> 6, j = tid & 63;
        int grow = row0 + r;
        int b = grow >> 10, l = grow & 1023;
        int bh = b * 8 + (j >> 3);
        int base = (bh * 1024 + l) * 8 + (j & 7);
        float num = Opart[base] + Opart[1048576 + base]
                  + Opart[2097152 + base] + Opart[3145728 + base];
        int sb = bh * 1024 + l;
        float den = ssum[sb] + ssum[131072 + sb] + ssum[262144 + sb] + ssum[393216 + sb];
        so[r][j] = num / den;
    }
    __syncthreads();
    int r = tid >> 6, c = tid & 63;
    float acc = 0.f;
#pragma unroll 8
    for (int j = 0; j < 64; ++j) acc = fmaf(so[r][j], sWo[j * 64 + c], acc);
    float x = X[(row0 + r) * 64 + c] + acc;
    float mean = wave_sum64(x) * (1.0f / 64.0f);
    float dx = x - mean;
    float var = wave_sum64(dx * dx) * (1.0f / 64.0f);
    X[(row0 + r) * 64 + c] = dx * rsqrtf(var + 1e-14f) * gamma[gi] + beta[gi];
}

// ---------------------------------------------------------------- FFN + residual + LN
__global__ __launch_bounds__(256) void ffn_ln_kernel(
    float* __restrict__ X, const float* __restrict__ W1, const float* __restrict__ b1,
    const float* __restrict__ W2, const float* __restrict__ b2,
    const float* __restrict__ gamma, const float* __restrict__ beta, int gi)
{
    __shared__ float sW1[8192];  // [c][j]
    __shared__ float sW2[8192];  // [j][c]
    __shared__ float sX[1024];
    __shared__ float sh[2048];
    int tid = threadIdx.x;
    for (int idx = tid; idx < 8192; idx += 256) { sW1[idx] = W1[idx]; sW2[idx] = W2[idx]; }
    int row0 = blockIdx.x * 16;
    for (int idx = tid; idx < 1024; idx += 256) sX[idx] = X[row0 * 64 + idx];
    __syncthreads();
    for (int idx = tid; idx < 2048; idx += 256) {
        int r = idx >> 7, j = idx & 127;
        float a = b1[j];
#pragma unroll 8
        for (int c = 0; c < 64; ++c) a = fmaf(sX[r * 64 + c], sW1[c * 128 + j], a);
        sh[idx] = fmaxf(a, 0.0f);
    }
    __syncthreads();
#pragma unroll
    for (int iter = 0; iter < 4; ++iter) {
        int idx = iter * 256 + tid;
        int r = idx >> 6, c = idx & 63;
        float a = b2[c];
#pragma unroll 8
        for (int j = 0; j < 128; ++j) a = fmaf(sh[r * 128 + j], sW2[j * 64 + c], a);
        float x = sX[idx] + a;
        float mean = wave_sum64(x) * (1.0f / 64.0f);
        float dx = x - mean;
        float var = wave_sum64(dx * dx) * (1.0f / 64.0f);
        X[row0 * 64 + idx] = dx * rsqrtf(var + 1e-14f) * gamma[gi] + beta[gi];
    }
}

// ---------------------------------------------------------------- pooling attention weights
__global__ __launch_bounds__(256) void aw_kernel(
    const float* __restrict__ X, const float* __restrict__ aW1, const float* __restrict__ ab1,
    const float* __restrict__ aW2, float* __restrict__ aw)
{
    __shared__ float sW[8192];   // aW1 [c][j]
    __shared__ float sX[1024];
    __shared__ float sh[2048];
    int tid = threadIdx.x;
    for (int idx = tid; idx < 8192; idx += 256) sW[idx] = aW1[idx];
    int row0 = blockIdx.x * 16;
    for (int idx = tid; idx < 1024; idx += 256) sX[idx] = X[row0 * 64 + idx];
    __syncthreads();
    for (int idx = tid; idx < 2048; idx += 256) {
        int r = idx >> 7, j = idx & 127;
        float a = ab1[j];
#pragma unroll 8
        for (int c = 0; c < 64; ++c) a = fmaf(sX[r * 64 + c], sW[c * 128 + j], a);
        sh[idx] = tanhf(a) * aW2[j];
    }
    __syncthreads();
    {
        int r = tid >> 4, jj = tid & 15;
        float s = 0.f;
#pragma unroll
        for (int t = 0; t < 8; ++t) s += sh[r * 128 + jj * 8 + t];
#pragma unroll
        for (int off = 8; off > 0; off >>= 1) s += __shfl_xor(s, off, 64);
        if (jj == 0) aw[row0 + r] = s;
    }
}

// ---------------------------------------------------------------- masked pool softmax + final head
__global__ __launch_bounds__(256) void pool_kernel(
    const float* __restrict__ X, const float* __restrict__ aw,
    const float* __restrict__ mask, const float* __restrict__ denc,
    const float* __restrict__ Wout, const float* __restrict__ bout, float* __restrict__ out)
{
    __shared__ float sp[1024];
    __shared__ float red[8];
    __shared__ float sf[4][64];
    int b = blockIdx.x, tid = threadIdx.x;
    float mymax = -INFINITY;
    for (int idx = tid; idx < 1024; idx += 256) {
        float s = (mask[b * 1024 + idx] != 0.0f) ? aw[b * 1024 + idx] : -1e30f;
        sp[idx] = s;
        mymax = fmaxf(mymax, s);
    }
#pragma unroll
    for (int off = 32; off > 0; off >>= 1) mymax = fmaxf(mymax, __shfl_xor(mymax, off, 64));
    if ((tid & 63) == 0) red[tid >> 6] = mymax;
    __syncthreads();
    float gmax = fmaxf(fmaxf(red[0], red[1]), fmaxf(red[2], red[3]));
    float mysum = 0.f;
    for (int idx = tid; idx < 1024; idx += 256) {
        float p = __expf(sp[idx] - gmax);
        sp[idx] = p;
        mysum += p;
    }
    mysum = wave_sum64(mysum);
    if ((tid & 63) == 0) red[4 + (tid >> 6)] = mysum;
    __syncthreads();
    float inv = 1.0f / (red[4] + red[5] + red[6] + red[7]);
    int c = tid & 63, part = tid >> 6;
    float f = 0.f;
    for (int l = part; l < 1024; l += 4) f = fmaf(sp[l], X[(b * 1024 + l) * 64 + c], f);
    sf[part][c] = f;
    __syncthreads();
    if (tid < 64) {
        float fc = (sf[0][tid] + sf[1][tid] + sf[2][tid] + sf[3][tid]) * inv;
        float contrib = fc * Wout[tid] + denc[b * 64 + tid] * Wout[64 + tid];
        contrib = wave_sum64(contrib);
        if (tid == 0) out[b] = 1.0f / (1.0f + __expf(-(contrib + bout[0])));
    }
}

// ---------------------------------------------------------------- launch
extern "C" void kernel_launch(void* const* d_in, const int* in_sizes, int n_in,
                              void* d_out, int out_size, void* d_ws, size_t ws_size,
                              hipStream_t stream)
{
    const float* demo  = (const float*)d_in[0];
    const float* times = (const float*)d_in[1];
    const float* values= (const float*)d_in[2];
    const int*   varis = (const int*)d_in[3];
    const float* emb   = (const float*)d_in[4];
    const float* vW1   = (const float*)d_in[5];
    const float* vb1   = (const float*)d_in[6];
    const float* vW2   = (const float*)d_in[7];
    const float* tW1   = (const float*)d_in[8];
    const float* tb1   = (const float*)d_in[9];
    const float* tW2   = (const float*)d_in[10];
    const float* Wq    = (const float*)d_in[11];
    const float* Wk    = (const float*)d_in[12];
    const float* Wv    = (const float*)d_in[13];
    const float* Wo    = (const float*)d_in[14];
    const float* W1    = (const float*)d_in[15];
    const float* b1    = (const float*)d_in[16];
    const float* W2    = (const float*)d_in[17];
    const float* b2    = (const float*)d_in[18];
    const float* gamma = (const float*)d_in[19];
    const float* beta  = (const float*)d_in[20];
    const float* aW1   = (const float*)d_in[21];
    const float* ab1   = (const float*)d_in[22];
    const float* aW2   = (const float*)d_in[23];
    const float* dW1   = (const float*)d_in[24];
    const float* db1   = (const float*)d_in[25];
    const float* dW2   = (const float*)d_in[26];
    const float* db2   = (const float*)d_in[27];
    const float* Wout  = (const float*)d_in[28];
    const float* bout  = (const float*)d_in[29];
    float* out = (float*)d_out;

    float* ws    = (float*)d_ws;
    float* X     = ws;                        // 1048576 f
    float* mask  = X + 1048576;               // 16384 f
    __bf16* qbf  = (__bf16*)(mask + 16384);   // 1048576 bf16 (524288 f)
    __bf16* kbf  = qbf + 1048576;             // 1048576 bf16
    __bf16* vtb  = kbf + 1048576;             // 1048576 bf16
    float* Opart = (float*)(vtb + 1048576);   // 4 x 1048576 f
    float* ssum  = Opart + 4194304;           // 4 x 131072 f
    float* awb   = ssum + 524288;             // 16384 f
    float* denc  = awb + 16384;               // 1024 f

    embed_kernel<<<4096, 256, 0, stream>>>(times, values, varis, emb, vW1, vb1, vW2, tW1, tb1, tW2, X, mask);
    demo_kernel<<<16, 128, 0, stream>>>(demo, dW1, db1, dW2, db2, denc);
    for (int i = 0; i < 2; ++i) {
        qkv_kernel<<<1024, 256, 0, stream>>>(X, mask, Wq + i * 4096, Wk + i * 4096, Wv + i * 4096,
                                             qbf, kbf, vtb);
        attn_mfma_kernel<<<2048, 256, 0, stream>>>(qbf, kbf, vtb, Opart, ssum);
        proj_ln_kernel<<<4096, 256, 0, stream>>>(X, Opart, ssum, Wo + i * 4096, gamma, beta, 2 * i);
        ffn_ln_kernel<<<1024, 256, 0, stream>>>(X, W1 + i * 8192, b1 + i * 128, W2 + i * 8192, b2 + i * 64,
                                                gamma, beta, 2 * i + 1);
    }
    aw_kernel<<<1024, 256, 0, stream>>>(X, aW1, ab1, aW2, awb);
    pool_kernel<<<16, 256, 0, stream>>>(X, awb, mask, denc, Wout, bout, out);
}